// Round 13
// baseline (648.681 us; speedup 1.0000x reference)
//
#include <hip/hip_runtime.h>

#define BS 100000
#define BQ 20000          // BS / 5
#define NWG 512           // workgroups in hist/fillA partition
#define CB  2048          // nodes per coarse bucket
#define NCMAX 256
#define NB_DEG 64         // degree bins (clamp at 63)
#define NWG2 128          // workgroups in degree-sort pass

typedef unsigned long long ull;

__device__ __forceinline__ float relu_(float v) { return fmaxf(v, 0.0f); }

// ---- 12-bit unsigned float codec (e5|m7, bias 112) ----
__device__ __forceinline__ unsigned enc12(float f) {
    unsigned u = __float_as_uint(f);
    if (u < 0x38000000u) return 0u;
    unsigned r = u - 0x38000000u;
    unsigned b = (r + 0x7FFFu + ((r >> 16) & 1u)) >> 16;
    return (b > 0xFFFu) ? 0xFFFu : b;
}
__device__ __forceinline__ float dec12(unsigned b) {
    return __uint_as_float((b << 16) + 0x38000000u);
}

// ================= binning =================
// tmp record: [dst&2047:11 @51][src:19 @32][wbits:32 @0]
// csr record (4 B): [src:19 @13][w_fix13 @0]
// order record (8 B): [deg @42][e0:23 @19][node:19 @0]

__global__ __launch_bounds__(256) void hist_kernel(
    const int* __restrict__ dst, int E, int NC, int per, int* __restrict__ hist2D)
{
    __shared__ int lc[NCMAX];
    int t = threadIdx.x, g = blockIdx.x;
    for (int i = t; i < NC; i += 256) lc[i] = 0;
    __syncthreads();
    int lo = g * per, hi = min(lo + per, E);
    if (lo < hi) {
        int nq = (hi - lo) >> 2;
        const int4* dst4 = (const int4*)(dst + lo);
        for (int q = t; q < nq; q += 256) {
            int4 d = dst4[q];
            atomicAdd(&lc[d.x >> 11], 1);
            atomicAdd(&lc[d.y >> 11], 1);
            atomicAdd(&lc[d.z >> 11], 1);
            atomicAdd(&lc[d.w >> 11], 1);
        }
        for (int i = lo + (nq << 2) + t; i < hi; i += 256)
            atomicAdd(&lc[dst[i] >> 11], 1);
    }
    __syncthreads();
    for (int b = t; b < NC; b += 256) hist2D[b * NWG + g] = lc[b];
}

__global__ __launch_bounds__(256) void reduce_kernel(
    const int* __restrict__ hist2D, int* __restrict__ bucketTot)
{
    __shared__ int s[256];
    int b = blockIdx.x, t = threadIdx.x;
    int sum = 0;
    for (int g = t; g < NWG; g += 256) sum += hist2D[(size_t)b * NWG + g];
    s[t] = sum;
    __syncthreads();
    for (int d = 128; d > 0; d >>= 1) {
        if (t < d) s[t] += s[t + d];
        __syncthreads();
    }
    if (t == 0) bucketTot[b] = s[0];
}

__global__ __launch_bounds__(256) void scanTot_kernel(
    const int* __restrict__ bucketTot, int NC, int* __restrict__ bucketBase)
{
    __shared__ int s[256];
    int t = threadIdx.x;
    int v = (t < NC) ? bucketTot[t] : 0;
    s[t] = v;
    __syncthreads();
    for (int d = 1; d < 256; d <<= 1) {
        int x = (t >= d) ? s[t - d] : 0;
        __syncthreads();
        s[t] += x;
        __syncthreads();
    }
    if (t < NC) bucketBase[t] = s[t] - v;
}

__global__ __launch_bounds__(NWG) void scanB_kernel(
    const int* __restrict__ hist2D, const int* __restrict__ bucketBase,
    int* __restrict__ wgbase)
{
    __shared__ int s[NWG];
    int b = blockIdx.x, g = threadIdx.x;
    int v = hist2D[(size_t)b * NWG + g];
    s[g] = v;
    __syncthreads();
    for (int d = 1; d < NWG; d <<= 1) {
        int x = (g >= d) ? s[g - d] : 0;
        __syncthreads();
        s[g] += x;
        __syncthreads();
    }
    wgbase[(size_t)b * NWG + g] = bucketBase[b] + s[g] - v;
}

__device__ __forceinline__ void fillA_one(int d, int s, float wv,
    int* cur, ull* __restrict__ tmp)
{
    int b = d >> 11;
    int pos = atomicAdd(&cur[b], 1);
    ull rec = (ull)__float_as_uint(wv)
            | ((ull)(unsigned int)s << 32)
            | ((ull)(unsigned int)(d & (CB - 1)) << 51);
    tmp[pos] = rec;
}

__global__ __launch_bounds__(256) void fillA_kernel(
    const int* __restrict__ src, const int* __restrict__ dst,
    const float* __restrict__ w, int E, int NC, int per,
    const int* __restrict__ wgbase, ull* __restrict__ tmp)
{
    __shared__ int cur[NCMAX];
    int t = threadIdx.x, g = blockIdx.x;
    for (int i = t; i < NC; i += 256) cur[i] = wgbase[(size_t)i * NWG + g];
    __syncthreads();
    int lo = g * per, hi = min(lo + per, E);
    if (lo >= hi) return;
    int nq = (hi - lo) >> 2;
    const int4* src4 = (const int4*)(src + lo);
    const int4* dst4 = (const int4*)(dst + lo);
    const float4* w4 = (const float4*)(w + lo);
    for (int q = t; q < nq; q += 256) {
        int4 d = dst4[q];
        int4 s = src4[q];
        float4 wv = w4[q];
        fillA_one(d.x, s.x, wv.x, cur, tmp);
        fillA_one(d.y, s.y, wv.y, cur, tmp);
        fillA_one(d.z, s.z, wv.z, cur, tmp);
        fillA_one(d.w, s.w, wv.w, cur, tmp);
    }
    for (int i = lo + (nq << 2) + t; i < hi; i += 256)
        fillA_one(dst[i], src[i], w[i], cur, tmp);
}

// one WG (512 thr) per coarse bucket: count -> scan(2048) -> 4-B csr scatter
__global__ __launch_bounds__(512) void fillA2B_kernel(
    const ull* __restrict__ tmp, const int* __restrict__ wgbase,
    int NC, int N, int E,
    unsigned* __restrict__ csr, int* __restrict__ offsets)
{
    __shared__ int cnt[CB];
    __shared__ int ssum[512];
    int b = blockIdx.x, t = threadIdx.x;
    int lo = wgbase[(size_t)b * NWG];
    int hi = (b == NC - 1) ? E : wgbase[(size_t)(b + 1) * NWG];
    int M = hi - lo;

    #pragma unroll
    for (int k = 0; k < CB / 512; k++) cnt[t + k * 512] = 0;
    __syncthreads();
    {
        int k = t;
        for (; k + 512 < M; k += 1024) {
            ull r0 = tmp[lo + k];
            ull r1 = tmp[lo + k + 512];
            atomicAdd(&cnt[(int)(r0 >> 51)], 1);
            atomicAdd(&cnt[(int)(r1 >> 51)], 1);
        }
        if (k < M) atomicAdd(&cnt[(int)(tmp[lo + k] >> 51)], 1);
    }
    __syncthreads();

    int base = t * 4;
    int loc[4];
    int run = 0;
    #pragma unroll
    for (int k = 0; k < 4; k++) { loc[k] = run; run += cnt[base + k]; }
    ssum[t] = run;
    __syncthreads();
    for (int d = 1; d < 512; d <<= 1) {
        int x = (t >= d) ? ssum[t - d] : 0;
        __syncthreads();
        ssum[t] += x;
        __syncthreads();
    }
    int excl = ssum[t] - run;

    int nodeBase = b * CB;
    #pragma unroll
    for (int k = 0; k < 4; k++) {
        int node = nodeBase + base + k;
        if (node < N) offsets[node] = lo + excl + loc[k];
        loc[k] += excl;
    }
    if (b == NC - 1 && t == 0) offsets[N] = E;
    __syncthreads();
    #pragma unroll
    for (int k = 0; k < 4; k++) cnt[base + k] = loc[k];
    __syncthreads();

    for (int e = lo + t; e < hi; e += 512) {
        ull rec = tmp[e];
        int dl = (int)(rec >> 51);
        int pos = atomicAdd(&cnt[dl], 1);
        float w = __uint_as_float((unsigned int)(rec & 0xFFFFFFFFull));
        unsigned wq = (unsigned)fmaf(w, 8191.0f, 0.5f);
        unsigned sidx = (unsigned)((rec >> 32) & 0x7FFFFull);
        csr[lo + pos] = (sidx << 13) | wq;
    }
}

// ================= degree-sorted node order =================

__global__ __launch_bounds__(256) void degHist_kernel(
    const int* __restrict__ offsets, int N, int per,
    int* __restrict__ dh, int* __restrict__ dhb)   // [NB_DEG][NWG2] each
{
    __shared__ int h[NB_DEG];
    __shared__ int hb[NB_DEG];
    int t = threadIdx.x, g = blockIdx.x;
    if (t < NB_DEG) { h[t] = 0; hb[t] = 0; }
    __syncthreads();
    int lo = g * per, hi = min(lo + per, N);
    for (int i = lo + t; i < hi; i += 256) {
        int deg = offsets[i + 1] - offsets[i];
        int bin = min(deg, NB_DEG - 1);
        atomicAdd(&h[bin], 1);
        if (i < BS) atomicAdd(&hb[bin], 1);
    }
    __syncthreads();
    if (t < NB_DEG) {
        dh[t * NWG2 + g] = h[t];
        dhb[t * NWG2 + g] = hb[t];
    }
}

// single-block in-place exclusive scan, n <= 8192
__global__ __launch_bounds__(1024) void scan8k_kernel(int* __restrict__ a, int n)
{
    __shared__ int s[1024];
    int t = threadIdx.x;
    int base = t * 8;
    int vals[8];
    int run = 0;
    #pragma unroll
    for (int k = 0; k < 8; k++) {
        int v = (base + k < n) ? a[base + k] : 0;
        vals[k] = run; run += v;
    }
    s[t] = run;
    __syncthreads();
    for (int d = 1; d < 1024; d <<= 1) {
        int x = (t >= d) ? s[t - d] : 0;
        __syncthreads();
        s[t] += x;
        __syncthreads();
    }
    int excl = s[t] - run;
    #pragma unroll
    for (int k = 0; k < 8; k++)
        if (base + k < n) a[base + k] = excl + vals[k];
}

__global__ __launch_bounds__(256) void degScatter_kernel(
    const int* __restrict__ offsets, int N, int per,
    const int* __restrict__ dh, const int* __restrict__ dhb,
    ull* __restrict__ order, ull* __restrict__ orderb)
{
    __shared__ int cur[NB_DEG];
    __shared__ int curb[NB_DEG];
    int t = threadIdx.x, g = blockIdx.x;
    if (t < NB_DEG) {
        cur[t] = dh[t * NWG2 + g];
        curb[t] = dhb[t * NWG2 + g];
    }
    __syncthreads();
    int lo = g * per, hi = min(lo + per, N);
    for (int i = lo + t; i < hi; i += 256) {
        int e0 = offsets[i];
        int deg = offsets[i + 1] - e0;
        int bin = min(deg, NB_DEG - 1);
        ull rec = (ull)(unsigned)i | ((ull)(unsigned)e0 << 19) | ((ull)(unsigned)deg << 42);
        int pos = atomicAdd(&cur[bin], 1);
        order[pos] = rec;
        if (i < BS) {
            int pos2 = atomicAdd(&curb[bin], 1);
            orderb[pos2] = rec;
        }
    }
}

// ---------------- z1 = relu(x @ Wl + bl) -> 12-bit packed rows ----------------
__global__ __launch_bounds__(256) void z1_kernel(
    const float* __restrict__ in,
    const float* __restrict__ we, const float* __restrict__ be,
    const float* __restrict__ wt, const float* __restrict__ bt,
    unsigned* __restrict__ zq, int n)
{
    __shared__ float sWe[32 * 32];
    __shared__ float sWt[32 * 8];
    __shared__ float sBe[32];
    __shared__ float sBt[8];
    for (int i = threadIdx.x; i < 32 * 32; i += 256) sWe[i] = we[i];
    for (int i = threadIdx.x; i < 32 * 8; i += 256) sWt[i] = wt[i];
    if (threadIdx.x < 32) sBe[threadIdx.x] = be[threadIdx.x];
    if (threadIdx.x < 8)  sBt[threadIdx.x] = bt[threadIdx.x];
    __syncthreads();

    int node = blockIdx.x * 256 + threadIdx.x;
    if (node >= n) return;

    float row[32];
    {
        const float4* rp = (const float4*)(in + (size_t)node * 32);
        #pragma unroll
        for (int q = 0; q < 8; q++) {
            float4 v = rp[q];
            row[4*q] = v.x; row[4*q+1] = v.y; row[4*q+2] = v.z; row[4*q+3] = v.w;
        }
    }

    float o[40];
    #pragma unroll
    for (int j = 0; j < 32; j++) o[j] = sBe[j];
    #pragma unroll
    for (int i = 0; i < 32; i++) {
        float v = row[i];
        #pragma unroll
        for (int j = 0; j < 32; j++) o[j] = fmaf(v, sWe[i * 32 + j], o[j]);
    }
    #pragma unroll
    for (int j = 0; j < 8; j++) o[32 + j] = sBt[j];
    #pragma unroll
    for (int i = 0; i < 32; i++) {
        float v = row[i];
        #pragma unroll
        for (int j = 0; j < 8; j++) o[32 + j] = fmaf(v, sWt[i * 8 + j], o[32 + j]);
    }

    unsigned b[40];
    #pragma unroll
    for (int i = 0; i < 40; i++) b[i] = enc12(relu_(o[i]));
    unsigned wd[16];
    #pragma unroll
    for (int k = 0; k < 5; k++) {
        wd[3*k+0] = b[8*k+0] | (b[8*k+1] << 12) | (b[8*k+2] << 24);
        wd[3*k+1] = (b[8*k+2] >> 8) | (b[8*k+3] << 4) | (b[8*k+4] << 16) | (b[8*k+5] << 28);
        wd[3*k+2] = (b[8*k+5] >> 4) | (b[8*k+6] << 8) | (b[8*k+7] << 20);
    }
    wd[15] = 0;
    uint4* zv = (uint4*)(zq + (size_t)node * 16);
    #pragma unroll
    for (int q = 0; q < 4; q++)
        zv[q] = make_uint4(wd[4*q], wd[4*q+1], wd[4*q+2], wd[4*q+3]);
}

// ---------------- decode+accumulate one edge ----------------
__device__ __forceinline__ void acc_edge(float* acc, float w,
    const uint4& A, const uint4& B, const uint4& C, const uint4& D)
{
    unsigned wds[15] = {A.x, A.y, A.z, A.w, B.x, B.y, B.z, B.w,
                        C.x, C.y, C.z, C.w, D.x, D.y, D.z};
    #pragma unroll
    for (int k = 0; k < 5; k++) {
        unsigned xw = wds[3*k+0], yw = wds[3*k+1], zw = wds[3*k+2];
        acc[8*k+0] = fmaf(w, dec12(xw & 0xFFFu),                       acc[8*k+0]);
        acc[8*k+1] = fmaf(w, dec12((xw >> 12) & 0xFFFu),               acc[8*k+1]);
        acc[8*k+2] = fmaf(w, dec12(((xw >> 24) | (yw << 8)) & 0xFFFu), acc[8*k+2]);
        acc[8*k+3] = fmaf(w, dec12((yw >> 4) & 0xFFFu),                acc[8*k+3]);
        acc[8*k+4] = fmaf(w, dec12((yw >> 16) & 0xFFFu),               acc[8*k+4]);
        acc[8*k+5] = fmaf(w, dec12(((yw >> 28) | (zw << 4)) & 0xFFFu), acc[8*k+5]);
        acc[8*k+6] = fmaf(w, dec12((zw >> 8) & 0xFFFu),                acc[8*k+6]);
        acc[8*k+7] = fmaf(w, dec12((zw >> 20) & 0xFFFu),               acc[8*k+7]);
    }
}

// ---------------- fused aggregate + finalize (+ optional fused z2 emit) ----------------
// Degree-ordered: thread gid processes order[gid] = [deg][e0][node].
template <int RW, int TIN, int TOFF, bool EMITZ>
__global__ __launch_bounds__(256) void fin_kernel(
    const float* __restrict__ in,
    const unsigned* __restrict__ zq,
    const ull* __restrict__ order,
    const unsigned* __restrict__ csr,        // 4-B records [src:19 @13][w13 @0]
    const float* __restrict__ wre, const float* __restrict__ bre,
    const float* __restrict__ wrt, const float* __restrict__ brt,
    const float* __restrict__ w2e, const float* __restrict__ b2e,
    const float* __restrict__ w2t, const float* __restrict__ b2t,
    float* __restrict__ outbuf, int nOut,
    unsigned* __restrict__ zq2,
    int n)
{
    __shared__ float sWe[64 * 32];
    __shared__ float sWt[(TIN + 8) * 8];
    __shared__ float sBe[32];
    __shared__ float sBt[8];
    __shared__ float sW2e[32 * 32];
    __shared__ float sW2t[8 * 8];
    __shared__ float sB2e[32];
    __shared__ float sB2t[8];
    for (int i = threadIdx.x; i < 64 * 32; i += 256) sWe[i] = wre[i];
    for (int i = threadIdx.x; i < (TIN + 8) * 8; i += 256) sWt[i] = wrt[i];
    if (threadIdx.x < 32) sBe[threadIdx.x] = bre[threadIdx.x];
    if (threadIdx.x < 8)  sBt[threadIdx.x] = brt[threadIdx.x];
    if (EMITZ) {
        for (int i = threadIdx.x; i < 32 * 32; i += 256) sW2e[i] = w2e[i];
        for (int i = threadIdx.x; i < 8 * 8; i += 256) sW2t[i] = w2t[i];
        if (threadIdx.x < 32) sB2e[threadIdx.x] = b2e[threadIdx.x];
        if (threadIdx.x < 8)  sB2t[threadIdx.x] = b2t[threadIdx.x];
    }
    __syncthreads();

    int gid = blockIdx.x * 256 + threadIdx.x;
    if (gid >= n) return;

    ull od = order[gid];
    int node = (int)(od & 0x7FFFFu);
    int e0   = (int)((od >> 19) & 0x7FFFFFu);
    int deg  = (int)(od >> 42);
    int e1   = e0 + deg;

    float acc[40];
    #pragma unroll
    for (int j = 0; j < 40; j++) acc[j] = 0.0f;
    float wsum = 1.0f;

    const float DW = 1.0f / 8191.0f;
    int e = e0;
    for (; e + 2 <= e1; e += 2) {
        unsigned pk0 = csr[e];
        unsigned pk1 = csr[e + 1];
        const uint4* p0 = (const uint4*)(zq + (size_t)(pk0 >> 13) * 16);
        const uint4* p1 = (const uint4*)(zq + (size_t)(pk1 >> 13) * 16);
        uint4 A0 = p0[0], B0 = p0[1], C0 = p0[2], D0 = p0[3];
        uint4 A1 = p1[0], B1 = p1[1], C1 = p1[2], D1 = p1[3];
        float w0 = (float)(pk0 & 8191u) * DW;
        float w1 = (float)(pk1 & 8191u) * DW;
        acc_edge(acc, w0, A0, B0, C0, D0);
        acc_edge(acc, w1, A1, B1, C1, D1);
        wsum += w0;
        wsum += w1;
    }
    if (e < e1) {
        unsigned pk = csr[e];
        const uint4* zp = (const uint4*)(zq + (size_t)(pk >> 13) * 16);
        uint4 A = zp[0], B = zp[1], C = zp[2], D = zp[3];
        float w = (float)(pk & 8191u) * DW;
        acc_edge(acc, w, A, B, C, D);
        wsum += w;
    }
    float inv = 1.0f / wsum;
    #pragma unroll
    for (int j = 0; j < 40; j++) acc[j] *= inv;

    float row[RW];
    {
        const float4* rp = (const float4*)(in + (size_t)node * RW);
        #pragma unroll
        for (int q = 0; q < RW / 4; q++) {
            float4 v = rp[q];
            row[4*q] = v.x; row[4*q+1] = v.y; row[4*q+2] = v.z; row[4*q+3] = v.w;
        }
    }

    float h[40];

    {
        float o[32];
        #pragma unroll
        for (int j = 0; j < 32; j++) o[j] = sBe[j];
        #pragma unroll
        for (int i = 0; i < 32; i++) {
            float v = row[i];
            #pragma unroll
            for (int j = 0; j < 32; j++) o[j] = fmaf(v, sWe[i * 32 + j], o[j]);
        }
        #pragma unroll
        for (int i = 0; i < 32; i++) {
            float v = acc[i];
            #pragma unroll
            for (int j = 0; j < 32; j++) o[j] = fmaf(v, sWe[(32 + i) * 32 + j], o[j]);
        }
        #pragma unroll
        for (int j = 0; j < 32; j++) h[j] = relu_(o[j]);
    }
    {
        float ot[8];
        #pragma unroll
        for (int j = 0; j < 8; j++) ot[j] = sBt[j];
        #pragma unroll
        for (int i = 0; i < TIN; i++) {
            float v = row[TOFF + i];
            #pragma unroll
            for (int j = 0; j < 8; j++) ot[j] = fmaf(v, sWt[i * 8 + j], ot[j]);
        }
        #pragma unroll
        for (int i = 0; i < 8; i++) {
            float v = acc[32 + i];
            #pragma unroll
            for (int j = 0; j < 8; j++) ot[j] = fmaf(v, sWt[(TIN + i) * 8 + j], ot[j]);
        }
        #pragma unroll
        for (int j = 0; j < 8; j++) h[32 + j] = relu_(ot[j]);
    }

    if (node < nOut) {
        float4* ov = (float4*)(outbuf + (size_t)node * 40);
        #pragma unroll
        for (int q = 0; q < 10; q++)
            ov[q] = make_float4(h[4*q], h[4*q+1], h[4*q+2], h[4*q+3]);
    }

    if (EMITZ) {
        float z2[40];
        #pragma unroll
        for (int j = 0; j < 32; j++) z2[j] = sB2e[j];
        #pragma unroll
        for (int i = 0; i < 32; i++) {
            float v = h[i];
            #pragma unroll
            for (int j = 0; j < 32; j++) z2[j] = fmaf(v, sW2e[i * 32 + j], z2[j]);
        }
        #pragma unroll
        for (int j = 0; j < 8; j++) z2[32 + j] = sB2t[j];
        #pragma unroll
        for (int i = 0; i < 8; i++) {
            float v = h[32 + i];
            #pragma unroll
            for (int j = 0; j < 8; j++) z2[32 + j] = fmaf(v, sW2t[i * 8 + j], z2[32 + j]);
        }
        unsigned b[40];
        #pragma unroll
        for (int i = 0; i < 40; i++) b[i] = enc12(relu_(z2[i]));
        unsigned wd[16];
        #pragma unroll
        for (int k = 0; k < 5; k++) {
            wd[3*k+0] = b[8*k+0] | (b[8*k+1] << 12) | (b[8*k+2] << 24);
            wd[3*k+1] = (b[8*k+2] >> 8) | (b[8*k+3] << 4) | (b[8*k+4] << 16) | (b[8*k+5] << 28);
            wd[3*k+2] = (b[8*k+5] >> 4) | (b[8*k+6] << 8) | (b[8*k+7] << 20);
        }
        wd[15] = 0;
        uint4* zv = (uint4*)(zq2 + (size_t)node * 16);
        #pragma unroll
        for (int q = 0; q < 4; q++)
            zv[q] = make_uint4(wd[4*q], wd[4*q+1], wd[4*q+2], wd[4*q+3]);
    }
}

// ---------------- loss ----------------

__device__ __forceinline__ void load40(const float* p, float* r) {
    const float4* v = (const float4*)p;
    #pragma unroll
    for (int q = 0; q < 10; q++) {
        float4 t = v[q];
        r[4*q] = t.x; r[4*q+1] = t.y; r[4*q+2] = t.z; r[4*q+3] = t.w;
    }
}

__device__ __forceinline__ float dot40(const float* a, const float* b) {
    float s = 0.0f;
    #pragma unroll
    for (int d = 0; d < 40; d++) s = fmaf(a[d], b[d], s);
    return s;
}

__device__ __forceinline__ void softmax5(const float l[5], float q[5]) {
    float m = l[0];
    #pragma unroll
    for (int c = 1; c < 5; c++) m = fmaxf(m, l[c]);
    float s = 0.0f;
    #pragma unroll
    for (int c = 0; c < 5; c++) { q[c] = expf(l[c] - m); s += q[c]; }
    float inv = 1.0f / s;
    #pragma unroll
    for (int c = 0; c < 5; c++) q[c] *= inv;
}

__device__ __forceinline__ float ent5(const float q[5]) {
    float e = 0.0f;
    #pragma unroll
    for (int c = 0; c < 5; c++) e += q[c] * logf(q[c] + 1e-20f);
    return e;
}

__device__ __forceinline__ float dot5(const float* a, const float* b) {
    float s = 0.0f;
    #pragma unroll
    for (int c = 0; c < 5; c++) s += a[c] * b[c];
    return s;
}

__global__ __launch_bounds__(256) void loss_kernel(
    const float* __restrict__ emb,
    const float* __restrict__ cent,
    const float* __restrict__ cent_t,
    float* __restrict__ out)
{
    __shared__ float sC[5 * 40];
    for (int i = threadIdx.x; i < 200; i += 256) {
        int c = i / 40, d = i % 40;
        sC[i] = (d < 32) ? cent[c * 32 + d] : cent_t[c * 8 + (d - 32)];
    }
    __syncthreads();

    int i = blockIdx.x * 256 + threadIdx.x;
    float contrib = 0.0f;
    if (i < BQ) {
        const float* base = emb + (size_t)i * 200;

        float ctr[40];
        load40(base, ctr);
        float l[5];
        #pragma unroll
        for (int c = 0; c < 5; c++) l[c] = dot40(ctr, sC + c * 40);
        float qc[5];
        softmax5(l, qc);
        float ent = ent5(qc);

        float rowv[40];
        load40(base + 40, rowv);
        float pd = dot40(ctr, rowv);
        #pragma unroll
        for (int c = 0; c < 5; c++) l[c] = dot40(rowv, sC + c * 40);
        float qp[5];
        softmax5(l, qp);
        float cpd = dot5(qc, qp);
        ent += ent5(qp);

        float nd = -1e30f, cnd = -1e30f;
        #pragma unroll
        for (int k = 0; k < 3; k++) {
            load40(base + (2 + k) * 40, rowv);
            nd = fmaxf(nd, dot40(ctr, rowv));
            #pragma unroll
            for (int c = 0; c < 5; c++) l[c] = dot40(rowv, sC + c * 40);
            float qn[5];
            softmax5(l, qn);
            cnd = fmaxf(cnd, dot5(qc, qn));
            ent += ent5(qn);
        }

        float mm  = fmaxf(nd - pd + 1.0f, 0.0f);
        float cmm = fmaxf(cnd - cpd + 1.0f, 0.0f);
        contrib = (mm + cmm) * (1.0f / (float)BQ) + 0.01f * (1.0f / (float)BS) * ent;
    }

    #pragma unroll
    for (int off = 32; off > 0; off >>= 1) contrib += __shfl_down(contrib, off);
    if ((threadIdx.x & 63) == 0) atomicAdd(out, contrib);
}

// ---------------- launch ----------------

extern "C" void kernel_launch(void* const* d_in, const int* in_sizes, int n_in,
                              void* d_out, int out_size, void* d_ws, size_t ws_size,
                              hipStream_t stream) {
    const float* x      = (const float*)d_in[0];
    const float* weight = (const float*)d_in[1];
    const float* e_w1l  = (const float*)d_in[2];
    const float* e_b1l  = (const float*)d_in[3];
    const float* e_w1r  = (const float*)d_in[4];
    const float* e_b1r  = (const float*)d_in[5];
    const float* e_w2l  = (const float*)d_in[6];
    const float* e_b2l  = (const float*)d_in[7];
    const float* e_w2r  = (const float*)d_in[8];
    const float* e_b2r  = (const float*)d_in[9];
    const float* t_w1l  = (const float*)d_in[10];
    const float* t_b1l  = (const float*)d_in[11];
    const float* t_w1r  = (const float*)d_in[12];
    const float* t_b1r  = (const float*)d_in[13];
    const float* t_w2l  = (const float*)d_in[14];
    const float* t_b2l  = (const float*)d_in[15];
    const float* t_w2r  = (const float*)d_in[16];
    const float* t_b2r  = (const float*)d_in[17];
    const float* cent   = (const float*)d_in[18];
    const float* cent_t = (const float*)d_in[19];
    const int*   eidx   = (const int*)d_in[20];

    const int E = in_sizes[20] / 2;
    const int N = in_sizes[0] / 32;
    const int* srcI = eidx;
    const int* dstI = eidx + E;
    float* out = (float*)d_out;

    const int NC = (N + CB - 1) / CB;                    // 245 coarse buckets
    const int per = (((E + NWG - 1) / NWG) + 3) & ~3;    // WG slice, multiple of 4
    const int perD = (N + NWG2 - 1) / NWG2;              // node slice for deg pass

    char* p = (char*)d_ws;
    auto alloc = [&](size_t bytes) -> char* {
        char* r = p;
        p += (bytes + 255) & ~(size_t)255;
        return r;
    };
    char* regionA = alloc((size_t)E * 8);                // tmp (64 MB) / zq1 (32 MB)
    ull*  tmp     = (ull*)regionA;
    unsigned* zq1 = (unsigned*)regionA;
    unsigned* zq2 = (unsigned*)alloc((size_t)N * 64);    // 32 MB
    float* hcat   = (float*)alloc((size_t)BS * 40 * 4);  // 16 MB
    float* emb    = (float*)alloc((size_t)BS * 40 * 4);  // 16 MB
    unsigned* csr = (unsigned*)alloc((size_t)E * 4);     // 32 MB
    int*   offsets= (int*)alloc((size_t)(N + 1) * 4);
    int*   hist2D = (int*)alloc((size_t)NC * NWG * 4);
    int*   wgbase = (int*)alloc((size_t)NC * NWG * 4);
    int*   bucketTot  = (int*)alloc((size_t)NC * 4);
    int*   bucketBase = (int*)alloc((size_t)NC * 4);
    ull*   order  = (ull*)alloc((size_t)N * 8);          // 4 MB
    ull*   orderb = (ull*)alloc((size_t)BS * 8);         // 0.8 MB
    int*   dh     = (int*)alloc((size_t)NB_DEG * NWG2 * 4);
    int*   dhb    = (int*)alloc((size_t)NB_DEG * NWG2 * 4);
    (void)ws_size;

    hipMemsetAsync(d_out, 0, sizeof(float), stream);

    // binning
    hist_kernel<<<NWG, 256, 0, stream>>>(dstI, E, NC, per, hist2D);
    reduce_kernel<<<NC, 256, 0, stream>>>(hist2D, bucketTot);
    scanTot_kernel<<<1, 256, 0, stream>>>(bucketTot, NC, bucketBase);
    scanB_kernel<<<NC, NWG, 0, stream>>>(hist2D, bucketBase, wgbase);
    fillA_kernel<<<NWG, 256, 0, stream>>>(srcI, dstI, weight, E, NC, per, wgbase, tmp);
    fillA2B_kernel<<<NC, 512, 0, stream>>>(tmp, wgbase, NC, N, E, csr, offsets);

    // degree-sorted node order (balances fin waves)
    degHist_kernel<<<NWG2, 256, 0, stream>>>(offsets, N, perD, dh, dhb);
    scan8k_kernel<<<1, 1024, 0, stream>>>(dh, NB_DEG * NWG2);
    scan8k_kernel<<<1, 1024, 0, stream>>>(dhb, NB_DEG * NWG2);
    degScatter_kernel<<<NWG2, 256, 0, stream>>>(offsets, N, perD, dh, dhb, order, orderb);

    const int nb = (N + 255) / 256;
    z1_kernel<<<nb, 256, 0, stream>>>(x, e_w1l, e_b1l, t_w1l, t_b1l, zq1, N);
    fin_kernel<32, 32, 0, true><<<nb, 256, 0, stream>>>(
        x, zq1, order, csr,
        e_w1r, e_b1r, t_w1r, t_b1r,
        e_w2l, e_b2l, t_w2l, t_b2l,
        hcat, BS, zq2, N);
    const int nb2 = (BS + 255) / 256;
    fin_kernel<40, 8, 32, false><<<nb2, 256, 0, stream>>>(
        hcat, zq2, orderb, csr,
        e_w2r, e_b2r, t_w2r, t_b2r,
        nullptr, nullptr, nullptr, nullptr,
        emb, BS, nullptr, BS);

    loss_kernel<<<(BQ + 255) / 256, 256, 0, stream>>>(emb, cent, cent_t, out);
}

// Round 14
// 609.576 us; speedup vs baseline: 1.0642x; 1.0642x over previous
//
#include <hip/hip_runtime.h>

#define BS 100000
#define BQ 20000          // BS / 5
#define NWG 512           // workgroups in hist/fillA partition
#define CB  2048          // nodes per coarse bucket
#define NCMAX 256

typedef unsigned long long ull;

__device__ __forceinline__ float relu_(float v) { return fmaxf(v, 0.0f); }

// ---- 12-bit unsigned float codec (e5|m7, bias 112) ----
__device__ __forceinline__ unsigned enc12(float f) {
    unsigned u = __float_as_uint(f);
    if (u < 0x38000000u) return 0u;
    unsigned r = u - 0x38000000u;
    unsigned b = (r + 0x7FFFu + ((r >> 16) & 1u)) >> 16;
    return (b > 0xFFFu) ? 0xFFFu : b;
}
__device__ __forceinline__ float dec12(unsigned b) {
    return __uint_as_float((b << 16) + 0x38000000u);
}

// ================= binning =================
// tmp record: [dst&2047:11 @51][src:19 @32][wbits:32 @0]
// csr record (4 B): [src:19 @13][w_fix13 @0]

__global__ __launch_bounds__(256) void hist_kernel(
    const int* __restrict__ dst, int E, int NC, int per, int* __restrict__ hist2D)
{
    __shared__ int lc[NCMAX];
    int t = threadIdx.x, g = blockIdx.x;
    for (int i = t; i < NC; i += 256) lc[i] = 0;
    __syncthreads();
    int lo = g * per, hi = min(lo + per, E);
    if (lo < hi) {
        int nq = (hi - lo) >> 2;
        const int4* dst4 = (const int4*)(dst + lo);
        for (int q = t; q < nq; q += 256) {
            int4 d = dst4[q];
            atomicAdd(&lc[d.x >> 11], 1);
            atomicAdd(&lc[d.y >> 11], 1);
            atomicAdd(&lc[d.z >> 11], 1);
            atomicAdd(&lc[d.w >> 11], 1);
        }
        for (int i = lo + (nq << 2) + t; i < hi; i += 256)
            atomicAdd(&lc[dst[i] >> 11], 1);
    }
    __syncthreads();
    for (int b = t; b < NC; b += 256) hist2D[b * NWG + g] = lc[b];
}

__global__ __launch_bounds__(256) void reduce_kernel(
    const int* __restrict__ hist2D, int* __restrict__ bucketTot)
{
    __shared__ int s[256];
    int b = blockIdx.x, t = threadIdx.x;
    int sum = 0;
    for (int g = t; g < NWG; g += 256) sum += hist2D[(size_t)b * NWG + g];
    s[t] = sum;
    __syncthreads();
    for (int d = 128; d > 0; d >>= 1) {
        if (t < d) s[t] += s[t + d];
        __syncthreads();
    }
    if (t == 0) bucketTot[b] = s[0];
}

__global__ __launch_bounds__(256) void scanTot_kernel(
    const int* __restrict__ bucketTot, int NC, int* __restrict__ bucketBase)
{
    __shared__ int s[256];
    int t = threadIdx.x;
    int v = (t < NC) ? bucketTot[t] : 0;
    s[t] = v;
    __syncthreads();
    for (int d = 1; d < 256; d <<= 1) {
        int x = (t >= d) ? s[t - d] : 0;
        __syncthreads();
        s[t] += x;
        __syncthreads();
    }
    if (t < NC) bucketBase[t] = s[t] - v;
}

__global__ __launch_bounds__(NWG) void scanB_kernel(
    const int* __restrict__ hist2D, const int* __restrict__ bucketBase,
    int* __restrict__ wgbase)
{
    __shared__ int s[NWG];
    int b = blockIdx.x, g = threadIdx.x;
    int v = hist2D[(size_t)b * NWG + g];
    s[g] = v;
    __syncthreads();
    for (int d = 1; d < NWG; d <<= 1) {
        int x = (g >= d) ? s[g - d] : 0;
        __syncthreads();
        s[g] += x;
        __syncthreads();
    }
    wgbase[(size_t)b * NWG + g] = bucketBase[b] + s[g] - v;
}

__device__ __forceinline__ void fillA_one(int d, int s, float wv,
    int* cur, ull* __restrict__ tmp)
{
    int b = d >> 11;
    int pos = atomicAdd(&cur[b], 1);
    ull rec = (ull)__float_as_uint(wv)
            | ((ull)(unsigned int)s << 32)
            | ((ull)(unsigned int)(d & (CB - 1)) << 51);
    tmp[pos] = rec;
}

__global__ __launch_bounds__(256) void fillA_kernel(
    const int* __restrict__ src, const int* __restrict__ dst,
    const float* __restrict__ w, int E, int NC, int per,
    const int* __restrict__ wgbase, ull* __restrict__ tmp)
{
    __shared__ int cur[NCMAX];
    int t = threadIdx.x, g = blockIdx.x;
    for (int i = t; i < NC; i += 256) cur[i] = wgbase[(size_t)i * NWG + g];
    __syncthreads();
    int lo = g * per, hi = min(lo + per, E);
    if (lo >= hi) return;
    int nq = (hi - lo) >> 2;
    const int4* src4 = (const int4*)(src + lo);
    const int4* dst4 = (const int4*)(dst + lo);
    const float4* w4 = (const float4*)(w + lo);
    for (int q = t; q < nq; q += 256) {
        int4 d = dst4[q];
        int4 s = src4[q];
        float4 wv = w4[q];
        fillA_one(d.x, s.x, wv.x, cur, tmp);
        fillA_one(d.y, s.y, wv.y, cur, tmp);
        fillA_one(d.z, s.z, wv.z, cur, tmp);
        fillA_one(d.w, s.w, wv.w, cur, tmp);
    }
    for (int i = lo + (nq << 2) + t; i < hi; i += 256)
        fillA_one(dst[i], src[i], w[i], cur, tmp);
}

// one WG (512 thr) per coarse bucket: count -> scan(2048) -> 4-B csr scatter
__global__ __launch_bounds__(512) void fillA2B_kernel(
    const ull* __restrict__ tmp, const int* __restrict__ wgbase,
    int NC, int N, int E,
    unsigned* __restrict__ csr, int* __restrict__ offsets)
{
    __shared__ int cnt[CB];
    __shared__ int ssum[512];
    int b = blockIdx.x, t = threadIdx.x;
    int lo = wgbase[(size_t)b * NWG];
    int hi = (b == NC - 1) ? E : wgbase[(size_t)(b + 1) * NWG];
    int M = hi - lo;

    #pragma unroll
    for (int k = 0; k < CB / 512; k++) cnt[t + k * 512] = 0;
    __syncthreads();
    {
        int k = t;
        for (; k + 512 < M; k += 1024) {
            ull r0 = tmp[lo + k];
            ull r1 = tmp[lo + k + 512];
            atomicAdd(&cnt[(int)(r0 >> 51)], 1);
            atomicAdd(&cnt[(int)(r1 >> 51)], 1);
        }
        if (k < M) atomicAdd(&cnt[(int)(tmp[lo + k] >> 51)], 1);
    }
    __syncthreads();

    int base = t * 4;
    int loc[4];
    int run = 0;
    #pragma unroll
    for (int k = 0; k < 4; k++) { loc[k] = run; run += cnt[base + k]; }
    ssum[t] = run;
    __syncthreads();
    for (int d = 1; d < 512; d <<= 1) {
        int x = (t >= d) ? ssum[t - d] : 0;
        __syncthreads();
        ssum[t] += x;
        __syncthreads();
    }
    int excl = ssum[t] - run;

    int nodeBase = b * CB;
    #pragma unroll
    for (int k = 0; k < 4; k++) {
        int node = nodeBase + base + k;
        if (node < N) offsets[node] = lo + excl + loc[k];
        loc[k] += excl;
    }
    if (b == NC - 1 && t == 0) offsets[N] = E;
    __syncthreads();
    #pragma unroll
    for (int k = 0; k < 4; k++) cnt[base + k] = loc[k];
    __syncthreads();

    for (int e = lo + t; e < hi; e += 512) {
        ull rec = tmp[e];
        int dl = (int)(rec >> 51);
        int pos = atomicAdd(&cnt[dl], 1);
        float w = __uint_as_float((unsigned int)(rec & 0xFFFFFFFFull));
        unsigned wq = (unsigned)fmaf(w, 8191.0f, 0.5f);
        unsigned sidx = (unsigned)((rec >> 32) & 0x7FFFFull);
        csr[lo + pos] = (sidx << 13) | wq;
    }
}

// ---------------- z1 = relu(x @ Wl + bl) -> 12-bit packed rows ----------------
__global__ __launch_bounds__(256) void z1_kernel(
    const float* __restrict__ in,
    const float* __restrict__ we, const float* __restrict__ be,
    const float* __restrict__ wt, const float* __restrict__ bt,
    unsigned* __restrict__ zq, int n)
{
    __shared__ float sWe[32 * 32];
    __shared__ float sWt[32 * 8];
    __shared__ float sBe[32];
    __shared__ float sBt[8];
    for (int i = threadIdx.x; i < 32 * 32; i += 256) sWe[i] = we[i];
    for (int i = threadIdx.x; i < 32 * 8; i += 256) sWt[i] = wt[i];
    if (threadIdx.x < 32) sBe[threadIdx.x] = be[threadIdx.x];
    if (threadIdx.x < 8)  sBt[threadIdx.x] = bt[threadIdx.x];
    __syncthreads();

    int node = blockIdx.x * 256 + threadIdx.x;
    if (node >= n) return;

    float row[32];
    {
        const float4* rp = (const float4*)(in + (size_t)node * 32);
        #pragma unroll
        for (int q = 0; q < 8; q++) {
            float4 v = rp[q];
            row[4*q] = v.x; row[4*q+1] = v.y; row[4*q+2] = v.z; row[4*q+3] = v.w;
        }
    }

    float o[40];
    #pragma unroll
    for (int j = 0; j < 32; j++) o[j] = sBe[j];
    #pragma unroll
    for (int i = 0; i < 32; i++) {
        float v = row[i];
        #pragma unroll
        for (int j = 0; j < 32; j++) o[j] = fmaf(v, sWe[i * 32 + j], o[j]);
    }
    #pragma unroll
    for (int j = 0; j < 8; j++) o[32 + j] = sBt[j];
    #pragma unroll
    for (int i = 0; i < 32; i++) {
        float v = row[i];
        #pragma unroll
        for (int j = 0; j < 8; j++) o[32 + j] = fmaf(v, sWt[i * 8 + j], o[32 + j]);
    }

    unsigned b[40];
    #pragma unroll
    for (int i = 0; i < 40; i++) b[i] = enc12(relu_(o[i]));
    unsigned wd[16];
    #pragma unroll
    for (int k = 0; k < 5; k++) {
        wd[3*k+0] = b[8*k+0] | (b[8*k+1] << 12) | (b[8*k+2] << 24);
        wd[3*k+1] = (b[8*k+2] >> 8) | (b[8*k+3] << 4) | (b[8*k+4] << 16) | (b[8*k+5] << 28);
        wd[3*k+2] = (b[8*k+5] >> 4) | (b[8*k+6] << 8) | (b[8*k+7] << 20);
    }
    wd[15] = 0;
    uint4* zv = (uint4*)(zq + (size_t)node * 16);
    #pragma unroll
    for (int q = 0; q < 4; q++)
        zv[q] = make_uint4(wd[4*q], wd[4*q+1], wd[4*q+2], wd[4*q+3]);
}

// ---------------- decode+accumulate one edge ----------------
__device__ __forceinline__ void acc_edge(float* acc, float w,
    const uint4& A, const uint4& B, const uint4& C, const uint4& D)
{
    unsigned wds[15] = {A.x, A.y, A.z, A.w, B.x, B.y, B.z, B.w,
                        C.x, C.y, C.z, C.w, D.x, D.y, D.z};
    #pragma unroll
    for (int k = 0; k < 5; k++) {
        unsigned xw = wds[3*k+0], yw = wds[3*k+1], zw = wds[3*k+2];
        acc[8*k+0] = fmaf(w, dec12(xw & 0xFFFu),                       acc[8*k+0]);
        acc[8*k+1] = fmaf(w, dec12((xw >> 12) & 0xFFFu),               acc[8*k+1]);
        acc[8*k+2] = fmaf(w, dec12(((xw >> 24) | (yw << 8)) & 0xFFFu), acc[8*k+2]);
        acc[8*k+3] = fmaf(w, dec12((yw >> 4) & 0xFFFu),                acc[8*k+3]);
        acc[8*k+4] = fmaf(w, dec12((yw >> 16) & 0xFFFu),               acc[8*k+4]);
        acc[8*k+5] = fmaf(w, dec12(((yw >> 28) | (zw << 4)) & 0xFFFu), acc[8*k+5]);
        acc[8*k+6] = fmaf(w, dec12((zw >> 8) & 0xFFFu),                acc[8*k+6]);
        acc[8*k+7] = fmaf(w, dec12((zw >> 20) & 0xFFFu),               acc[8*k+7]);
    }
}

// ---------------- fused aggregate + finalize (+ optional fused z2 emit) ----------------
// Block-local degree sort: bitonic-sort the block's 256 (deg,e0,lidx) tuples so
// each wave processes near-equal degrees; all accesses stay in the block's
// original 256-node window (locality preserved; round-13 lesson).
template <int RW, int TIN, int TOFF, bool EMITZ>
__global__ __launch_bounds__(256) void fin_kernel(
    const float* __restrict__ in,
    const unsigned* __restrict__ zq,
    const int* __restrict__ offsets,
    const unsigned* __restrict__ csr,        // 4-B records [src:19 @13][w13 @0]
    const float* __restrict__ wre, const float* __restrict__ bre,
    const float* __restrict__ wrt, const float* __restrict__ brt,
    const float* __restrict__ w2e, const float* __restrict__ b2e,
    const float* __restrict__ w2t, const float* __restrict__ b2t,
    float* __restrict__ outbuf, int nOut,
    unsigned* __restrict__ zq2,
    int n)
{
    __shared__ float sWe[64 * 32];
    __shared__ float sWt[(TIN + 8) * 8];
    __shared__ float sBe[32];
    __shared__ float sBt[8];
    __shared__ float sW2e[32 * 32];
    __shared__ float sW2t[8 * 8];
    __shared__ float sB2e[32];
    __shared__ float sB2t[8];
    __shared__ ull sOrd[256];
    int t = threadIdx.x;
    for (int i = t; i < 64 * 32; i += 256) sWe[i] = wre[i];
    for (int i = t; i < (TIN + 8) * 8; i += 256) sWt[i] = wrt[i];
    if (t < 32) sBe[t] = bre[t];
    if (t < 8)  sBt[t] = brt[t];
    if (EMITZ) {
        for (int i = t; i < 32 * 32; i += 256) sW2e[i] = w2e[i];
        for (int i = t; i < 8 * 8; i += 256) sW2t[i] = w2t[i];
        if (t < 32) sB2e[t] = b2e[t];
        if (t < 8)  sB2t[t] = b2t[t];
    }

    // load (deg, e0) for this block's 256 nodes (coalesced), then sort by degree
    {
        int node0 = blockIdx.x * 256 + t;
        unsigned e0_ = 0, deg_ = 0;
        if (node0 < n) {
            int a = offsets[node0];
            int b2 = offsets[node0 + 1];
            e0_ = (unsigned)a;
            deg_ = (unsigned)(b2 - a);
        }
        sOrd[t] = ((ull)deg_ << 31) | ((ull)e0_ << 8) | (unsigned)t;
    }
    __syncthreads();
    for (int k = 2; k <= 256; k <<= 1) {
        for (int j = k >> 1; j > 0; j >>= 1) {
            int ixj = t ^ j;
            if (ixj > t) {
                ull a = sOrd[t], b2 = sOrd[ixj];
                bool up = ((t & k) == 0);
                if ((a > b2) == up) { sOrd[t] = b2; sOrd[ixj] = a; }
            }
            __syncthreads();
        }
    }

    ull od = sOrd[t];
    int node = blockIdx.x * 256 + (int)(od & 0xFFu);
    if (node >= n) return;
    int e0  = (int)((od >> 8) & 0x7FFFFFu);
    int deg = (int)(od >> 31);
    int e1  = e0 + deg;

    float acc[40];
    #pragma unroll
    for (int j = 0; j < 40; j++) acc[j] = 0.0f;
    float wsum = 1.0f;

    const float DW = 1.0f / 8191.0f;
    int e = e0;
    for (; e + 2 <= e1; e += 2) {
        unsigned pk0 = csr[e];
        unsigned pk1 = csr[e + 1];
        const uint4* p0 = (const uint4*)(zq + (size_t)(pk0 >> 13) * 16);
        const uint4* p1 = (const uint4*)(zq + (size_t)(pk1 >> 13) * 16);
        uint4 A0 = p0[0], B0 = p0[1], C0 = p0[2], D0 = p0[3];
        uint4 A1 = p1[0], B1 = p1[1], C1 = p1[2], D1 = p1[3];
        float w0 = (float)(pk0 & 8191u) * DW;
        float w1 = (float)(pk1 & 8191u) * DW;
        acc_edge(acc, w0, A0, B0, C0, D0);
        acc_edge(acc, w1, A1, B1, C1, D1);
        wsum += w0;
        wsum += w1;
    }
    if (e < e1) {
        unsigned pk = csr[e];
        const uint4* zp = (const uint4*)(zq + (size_t)(pk >> 13) * 16);
        uint4 A = zp[0], B = zp[1], C = zp[2], D = zp[3];
        float w = (float)(pk & 8191u) * DW;
        acc_edge(acc, w, A, B, C, D);
        wsum += w;
    }
    float inv = 1.0f / wsum;
    #pragma unroll
    for (int j = 0; j < 40; j++) acc[j] *= inv;

    float row[RW];
    {
        const float4* rp = (const float4*)(in + (size_t)node * RW);
        #pragma unroll
        for (int q = 0; q < RW / 4; q++) {
            float4 v = rp[q];
            row[4*q] = v.x; row[4*q+1] = v.y; row[4*q+2] = v.z; row[4*q+3] = v.w;
        }
    }

    float h[40];

    {
        float o[32];
        #pragma unroll
        for (int j = 0; j < 32; j++) o[j] = sBe[j];
        #pragma unroll
        for (int i = 0; i < 32; i++) {
            float v = row[i];
            #pragma unroll
            for (int j = 0; j < 32; j++) o[j] = fmaf(v, sWe[i * 32 + j], o[j]);
        }
        #pragma unroll
        for (int i = 0; i < 32; i++) {
            float v = acc[i];
            #pragma unroll
            for (int j = 0; j < 32; j++) o[j] = fmaf(v, sWe[(32 + i) * 32 + j], o[j]);
        }
        #pragma unroll
        for (int j = 0; j < 32; j++) h[j] = relu_(o[j]);
    }
    {
        float ot[8];
        #pragma unroll
        for (int j = 0; j < 8; j++) ot[j] = sBt[j];
        #pragma unroll
        for (int i = 0; i < TIN; i++) {
            float v = row[TOFF + i];
            #pragma unroll
            for (int j = 0; j < 8; j++) ot[j] = fmaf(v, sWt[i * 8 + j], ot[j]);
        }
        #pragma unroll
        for (int i = 0; i < 8; i++) {
            float v = acc[32 + i];
            #pragma unroll
            for (int j = 0; j < 8; j++) ot[j] = fmaf(v, sWt[(TIN + i) * 8 + j], ot[j]);
        }
        #pragma unroll
        for (int j = 0; j < 8; j++) h[32 + j] = relu_(ot[j]);
    }

    if (node < nOut) {
        float4* ov = (float4*)(outbuf + (size_t)node * 40);
        #pragma unroll
        for (int q = 0; q < 10; q++)
            ov[q] = make_float4(h[4*q], h[4*q+1], h[4*q+2], h[4*q+3]);
    }

    if (EMITZ) {
        float z2[40];
        #pragma unroll
        for (int j = 0; j < 32; j++) z2[j] = sB2e[j];
        #pragma unroll
        for (int i = 0; i < 32; i++) {
            float v = h[i];
            #pragma unroll
            for (int j = 0; j < 32; j++) z2[j] = fmaf(v, sW2e[i * 32 + j], z2[j]);
        }
        #pragma unroll
        for (int j = 0; j < 8; j++) z2[32 + j] = sB2t[j];
        #pragma unroll
        for (int i = 0; i < 8; i++) {
            float v = h[32 + i];
            #pragma unroll
            for (int j = 0; j < 8; j++) z2[32 + j] = fmaf(v, sW2t[i * 8 + j], z2[32 + j]);
        }
        unsigned b[40];
        #pragma unroll
        for (int i = 0; i < 40; i++) b[i] = enc12(relu_(z2[i]));
        unsigned wd[16];
        #pragma unroll
        for (int k = 0; k < 5; k++) {
            wd[3*k+0] = b[8*k+0] | (b[8*k+1] << 12) | (b[8*k+2] << 24);
            wd[3*k+1] = (b[8*k+2] >> 8) | (b[8*k+3] << 4) | (b[8*k+4] << 16) | (b[8*k+5] << 28);
            wd[3*k+2] = (b[8*k+5] >> 4) | (b[8*k+6] << 8) | (b[8*k+7] << 20);
        }
        wd[15] = 0;
        uint4* zv = (uint4*)(zq2 + (size_t)node * 16);
        #pragma unroll
        for (int q = 0; q < 4; q++)
            zv[q] = make_uint4(wd[4*q], wd[4*q+1], wd[4*q+2], wd[4*q+3]);
    }
}

// ---------------- loss ----------------

__device__ __forceinline__ void load40(const float* p, float* r) {
    const float4* v = (const float4*)p;
    #pragma unroll
    for (int q = 0; q < 10; q++) {
        float4 t = v[q];
        r[4*q] = t.x; r[4*q+1] = t.y; r[4*q+2] = t.z; r[4*q+3] = t.w;
    }
}

__device__ __forceinline__ float dot40(const float* a, const float* b) {
    float s = 0.0f;
    #pragma unroll
    for (int d = 0; d < 40; d++) s = fmaf(a[d], b[d], s);
    return s;
}

__device__ __forceinline__ void softmax5(const float l[5], float q[5]) {
    float m = l[0];
    #pragma unroll
    for (int c = 1; c < 5; c++) m = fmaxf(m, l[c]);
    float s = 0.0f;
    #pragma unroll
    for (int c = 0; c < 5; c++) { q[c] = expf(l[c] - m); s += q[c]; }
    float inv = 1.0f / s;
    #pragma unroll
    for (int c = 0; c < 5; c++) q[c] *= inv;
}

__device__ __forceinline__ float ent5(const float q[5]) {
    float e = 0.0f;
    #pragma unroll
    for (int c = 0; c < 5; c++) e += q[c] * logf(q[c] + 1e-20f);
    return e;
}

__device__ __forceinline__ float dot5(const float* a, const float* b) {
    float s = 0.0f;
    #pragma unroll
    for (int c = 0; c < 5; c++) s += a[c] * b[c];
    return s;
}

__global__ __launch_bounds__(256) void loss_kernel(
    const float* __restrict__ emb,
    const float* __restrict__ cent,
    const float* __restrict__ cent_t,
    float* __restrict__ out)
{
    __shared__ float sC[5 * 40];
    for (int i = threadIdx.x; i < 200; i += 256) {
        int c = i / 40, d = i % 40;
        sC[i] = (d < 32) ? cent[c * 32 + d] : cent_t[c * 8 + (d - 32)];
    }
    __syncthreads();

    int i = blockIdx.x * 256 + threadIdx.x;
    float contrib = 0.0f;
    if (i < BQ) {
        const float* base = emb + (size_t)i * 200;

        float ctr[40];
        load40(base, ctr);
        float l[5];
        #pragma unroll
        for (int c = 0; c < 5; c++) l[c] = dot40(ctr, sC + c * 40);
        float qc[5];
        softmax5(l, qc);
        float ent = ent5(qc);

        float rowv[40];
        load40(base + 40, rowv);
        float pd = dot40(ctr, rowv);
        #pragma unroll
        for (int c = 0; c < 5; c++) l[c] = dot40(rowv, sC + c * 40);
        float qp[5];
        softmax5(l, qp);
        float cpd = dot5(qc, qp);
        ent += ent5(qp);

        float nd = -1e30f, cnd = -1e30f;
        #pragma unroll
        for (int k = 0; k < 3; k++) {
            load40(base + (2 + k) * 40, rowv);
            nd = fmaxf(nd, dot40(ctr, rowv));
            #pragma unroll
            for (int c = 0; c < 5; c++) l[c] = dot40(rowv, sC + c * 40);
            float qn[5];
            softmax5(l, qn);
            cnd = fmaxf(cnd, dot5(qc, qn));
            ent += ent5(qn);
        }

        float mm  = fmaxf(nd - pd + 1.0f, 0.0f);
        float cmm = fmaxf(cnd - cpd + 1.0f, 0.0f);
        contrib = (mm + cmm) * (1.0f / (float)BQ) + 0.01f * (1.0f / (float)BS) * ent;
    }

    #pragma unroll
    for (int off = 32; off > 0; off >>= 1) contrib += __shfl_down(contrib, off);
    if ((threadIdx.x & 63) == 0) atomicAdd(out, contrib);
}

// ---------------- launch ----------------

extern "C" void kernel_launch(void* const* d_in, const int* in_sizes, int n_in,
                              void* d_out, int out_size, void* d_ws, size_t ws_size,
                              hipStream_t stream) {
    const float* x      = (const float*)d_in[0];
    const float* weight = (const float*)d_in[1];
    const float* e_w1l  = (const float*)d_in[2];
    const float* e_b1l  = (const float*)d_in[3];
    const float* e_w1r  = (const float*)d_in[4];
    const float* e_b1r  = (const float*)d_in[5];
    const float* e_w2l  = (const float*)d_in[6];
    const float* e_b2l  = (const float*)d_in[7];
    const float* e_w2r  = (const float*)d_in[8];
    const float* e_b2r  = (const float*)d_in[9];
    const float* t_w1l  = (const float*)d_in[10];
    const float* t_b1l  = (const float*)d_in[11];
    const float* t_w1r  = (const float*)d_in[12];
    const float* t_b1r  = (const float*)d_in[13];
    const float* t_w2l  = (const float*)d_in[14];
    const float* t_b2l  = (const float*)d_in[15];
    const float* t_w2r  = (const float*)d_in[16];
    const float* t_b2r  = (const float*)d_in[17];
    const float* cent   = (const float*)d_in[18];
    const float* cent_t = (const float*)d_in[19];
    const int*   eidx   = (const int*)d_in[20];

    const int E = in_sizes[20] / 2;
    const int N = in_sizes[0] / 32;
    const int* srcI = eidx;
    const int* dstI = eidx + E;
    float* out = (float*)d_out;

    const int NC = (N + CB - 1) / CB;                    // 245 coarse buckets
    const int per = (((E + NWG - 1) / NWG) + 3) & ~3;    // WG slice, multiple of 4

    char* p = (char*)d_ws;
    auto alloc = [&](size_t bytes) -> char* {
        char* r = p;
        p += (bytes + 255) & ~(size_t)255;
        return r;
    };
    char* regionA = alloc((size_t)E * 8);                // tmp (64 MB) / zq1 (32 MB)
    ull*  tmp     = (ull*)regionA;
    unsigned* zq1 = (unsigned*)regionA;
    unsigned* zq2 = (unsigned*)alloc((size_t)N * 64);    // 32 MB
    float* hcat   = (float*)alloc((size_t)BS * 40 * 4);  // 16 MB
    float* emb    = (float*)alloc((size_t)BS * 40 * 4);  // 16 MB
    unsigned* csr = (unsigned*)alloc((size_t)E * 4);     // 32 MB
    int*   offsets= (int*)alloc((size_t)(N + 1) * 4);
    int*   hist2D = (int*)alloc((size_t)NC * NWG * 4);
    int*   wgbase = (int*)alloc((size_t)NC * NWG * 4);
    int*   bucketTot  = (int*)alloc((size_t)NC * 4);
    int*   bucketBase = (int*)alloc((size_t)NC * 4);
    (void)ws_size;

    hipMemsetAsync(d_out, 0, sizeof(float), stream);

    // binning
    hist_kernel<<<NWG, 256, 0, stream>>>(dstI, E, NC, per, hist2D);
    reduce_kernel<<<NC, 256, 0, stream>>>(hist2D, bucketTot);
    scanTot_kernel<<<1, 256, 0, stream>>>(bucketTot, NC, bucketBase);
    scanB_kernel<<<NC, NWG, 0, stream>>>(hist2D, bucketBase, wgbase);
    fillA_kernel<<<NWG, 256, 0, stream>>>(srcI, dstI, weight, E, NC, per, wgbase, tmp);
    fillA2B_kernel<<<NC, 512, 0, stream>>>(tmp, wgbase, NC, N, E, csr, offsets);

    const int nb = (N + 255) / 256;
    z1_kernel<<<nb, 256, 0, stream>>>(x, e_w1l, e_b1l, t_w1l, t_b1l, zq1, N);
    fin_kernel<32, 32, 0, true><<<nb, 256, 0, stream>>>(
        x, zq1, offsets, csr,
        e_w1r, e_b1r, t_w1r, t_b1r,
        e_w2l, e_b2l, t_w2l, t_b2l,
        hcat, BS, zq2, N);
    const int nb2 = (BS + 255) / 256;
    fin_kernel<40, 8, 32, false><<<nb2, 256, 0, stream>>>(
        hcat, zq2, offsets, csr,
        e_w2r, e_b2r, t_w2r, t_b2r,
        nullptr, nullptr, nullptr, nullptr,
        emb, BS, nullptr, BS);

    loss_kernel<<<(BQ + 255) / 256, 256, 0, stream>>>(emb, cent, cent_t, out);
}

// Round 15
// 562.100 us; speedup vs baseline: 1.1540x; 1.0845x over previous
//
#include <hip/hip_runtime.h>

#define BS 100000
#define BQ 20000          // BS / 5
#define NWG 256           // workgroups in hist/fillA partition (1024 thr each)
#define CB  2048          // nodes per coarse bucket
#define NCMAX 256

typedef unsigned long long ull;

__device__ __forceinline__ float relu_(float v) { return fmaxf(v, 0.0f); }

// ---- 12-bit unsigned float codec (e5|m7, bias 112) ----
__device__ __forceinline__ unsigned enc12(float f) {
    unsigned u = __float_as_uint(f);
    if (u < 0x38000000u) return 0u;
    unsigned r = u - 0x38000000u;
    unsigned b = (r + 0x7FFFu + ((r >> 16) & 1u)) >> 16;
    return (b > 0xFFFu) ? 0xFFFu : b;
}
__device__ __forceinline__ float dec12(unsigned b) {
    return __uint_as_float((b << 16) + 0x38000000u);
}

// ================= binning =================
// tmp record: [dst&2047:11 @51][src:19 @32][wbits:32 @0]
// csr record (4 B): [src:19 @13][w_fix13 @0]

__global__ __launch_bounds__(1024) void hist_kernel(
    const int* __restrict__ dst, int E, int NC, int per, int* __restrict__ hist2D)
{
    __shared__ int lc[NCMAX];
    int t = threadIdx.x, g = blockIdx.x;
    for (int i = t; i < NC; i += 1024) lc[i] = 0;
    __syncthreads();
    int lo = g * per, hi = min(lo + per, E);
    if (lo < hi) {
        int nq = (hi - lo) >> 2;
        const int4* dst4 = (const int4*)(dst + lo);
        for (int q = t; q < nq; q += 1024) {
            int4 d = dst4[q];
            atomicAdd(&lc[d.x >> 11], 1);
            atomicAdd(&lc[d.y >> 11], 1);
            atomicAdd(&lc[d.z >> 11], 1);
            atomicAdd(&lc[d.w >> 11], 1);
        }
        for (int i = lo + (nq << 2) + t; i < hi; i += 1024)
            atomicAdd(&lc[dst[i] >> 11], 1);
    }
    __syncthreads();
    for (int b = t; b < NC; b += 1024) hist2D[b * NWG + g] = lc[b];
}

__global__ __launch_bounds__(256) void reduce_kernel(
    const int* __restrict__ hist2D, int* __restrict__ bucketTot)
{
    __shared__ int s[256];
    int b = blockIdx.x, t = threadIdx.x;
    int sum = 0;
    for (int g = t; g < NWG; g += 256) sum += hist2D[(size_t)b * NWG + g];
    s[t] = sum;
    __syncthreads();
    for (int d = 128; d > 0; d >>= 1) {
        if (t < d) s[t] += s[t + d];
        __syncthreads();
    }
    if (t == 0) bucketTot[b] = s[0];
}

__global__ __launch_bounds__(256) void scanTot_kernel(
    const int* __restrict__ bucketTot, int NC, int* __restrict__ bucketBase)
{
    __shared__ int s[256];
    int t = threadIdx.x;
    int v = (t < NC) ? bucketTot[t] : 0;
    s[t] = v;
    __syncthreads();
    for (int d = 1; d < 256; d <<= 1) {
        int x = (t >= d) ? s[t - d] : 0;
        __syncthreads();
        s[t] += x;
        __syncthreads();
    }
    if (t < NC) bucketBase[t] = s[t] - v;
}

__global__ __launch_bounds__(NWG) void scanB_kernel(
    const int* __restrict__ hist2D, const int* __restrict__ bucketBase,
    int* __restrict__ wgbase)
{
    __shared__ int s[NWG];
    int b = blockIdx.x, g = threadIdx.x;
    int v = hist2D[(size_t)b * NWG + g];
    s[g] = v;
    __syncthreads();
    for (int d = 1; d < NWG; d <<= 1) {
        int x = (g >= d) ? s[g - d] : 0;
        __syncthreads();
        s[g] += x;
        __syncthreads();
    }
    wgbase[(size_t)b * NWG + g] = bucketBase[b] + s[g] - v;
}

__device__ __forceinline__ void fillA_one(int d, int s, float wv,
    int* cur, ull* __restrict__ tmp)
{
    int b = d >> 11;
    int pos = atomicAdd(&cur[b], 1);
    ull rec = (ull)__float_as_uint(wv)
            | ((ull)(unsigned int)s << 32)
            | ((ull)(unsigned int)(d & (CB - 1)) << 51);
    tmp[pos] = rec;
}

__global__ __launch_bounds__(1024) void fillA_kernel(
    const int* __restrict__ src, const int* __restrict__ dst,
    const float* __restrict__ w, int E, int NC, int per,
    const int* __restrict__ wgbase, ull* __restrict__ tmp)
{
    __shared__ int cur[NCMAX];
    int t = threadIdx.x, g = blockIdx.x;
    for (int i = t; i < NC; i += 1024) cur[i] = wgbase[(size_t)i * NWG + g];
    __syncthreads();
    int lo = g * per, hi = min(lo + per, E);
    if (lo >= hi) return;
    int nq = (hi - lo) >> 2;
    const int4* src4 = (const int4*)(src + lo);
    const int4* dst4 = (const int4*)(dst + lo);
    const float4* w4 = (const float4*)(w + lo);
    for (int q = t; q < nq; q += 1024) {
        int4 d = dst4[q];
        int4 s = src4[q];
        float4 wv = w4[q];
        fillA_one(d.x, s.x, wv.x, cur, tmp);
        fillA_one(d.y, s.y, wv.y, cur, tmp);
        fillA_one(d.z, s.z, wv.z, cur, tmp);
        fillA_one(d.w, s.w, wv.w, cur, tmp);
    }
    for (int i = lo + (nq << 2) + t; i < hi; i += 1024)
        fillA_one(dst[i], src[i], w[i], cur, tmp);
}

// one WG (1024 thr) per coarse bucket: count -> scan(2048) -> 4-B csr scatter
__global__ __launch_bounds__(1024) void fillA2B_kernel(
    const ull* __restrict__ tmp, const int* __restrict__ wgbase,
    int NC, int N, int E,
    unsigned* __restrict__ csr, int* __restrict__ offsets)
{
    __shared__ int cnt[CB];
    __shared__ int ssum[1024];
    int b = blockIdx.x, t = threadIdx.x;
    int lo = wgbase[(size_t)b * NWG];
    int hi = (b == NC - 1) ? E : wgbase[(size_t)(b + 1) * NWG];
    int M = hi - lo;

    cnt[t] = 0;
    cnt[t + 1024] = 0;
    __syncthreads();
    {
        int k = t;
        for (; k + 1024 < M; k += 2048) {
            ull r0 = tmp[lo + k];
            ull r1 = tmp[lo + k + 1024];
            atomicAdd(&cnt[(int)(r0 >> 51)], 1);
            atomicAdd(&cnt[(int)(r1 >> 51)], 1);
        }
        if (k < M) atomicAdd(&cnt[(int)(tmp[lo + k] >> 51)], 1);
    }
    __syncthreads();

    int base = t * 2;
    int loc0 = 0, loc1;
    int run;
    {
        int c0 = cnt[base], c1 = cnt[base + 1];
        loc1 = c0;
        run = c0 + c1;
    }
    ssum[t] = run;
    __syncthreads();
    for (int d = 1; d < 1024; d <<= 1) {
        int x = (t >= d) ? ssum[t - d] : 0;
        __syncthreads();
        ssum[t] += x;
        __syncthreads();
    }
    int excl = ssum[t] - run;
    loc0 += excl;
    loc1 += excl;

    int nodeBase = b * CB;
    {
        int node = nodeBase + base;
        if (node < N) offsets[node] = lo + loc0;
        if (node + 1 < N) offsets[node + 1] = lo + loc1;
    }
    if (b == NC - 1 && t == 0) offsets[N] = E;
    __syncthreads();
    cnt[base] = loc0;
    cnt[base + 1] = loc1;
    __syncthreads();

    for (int e = lo + t; e < hi; e += 1024) {
        ull rec = tmp[e];
        int dl = (int)(rec >> 51);
        int pos = atomicAdd(&cnt[dl], 1);
        float w = __uint_as_float((unsigned int)(rec & 0xFFFFFFFFull));
        unsigned wq = (unsigned)fmaf(w, 8191.0f, 0.5f);
        unsigned sidx = (unsigned)((rec >> 32) & 0x7FFFFull);
        csr[lo + pos] = (sidx << 13) | wq;
    }
}

// ---------------- z1 = relu(x @ Wl + bl) -> 12-bit packed rows ----------------
__global__ __launch_bounds__(256) void z1_kernel(
    const float* __restrict__ in,
    const float* __restrict__ we, const float* __restrict__ be,
    const float* __restrict__ wt, const float* __restrict__ bt,
    unsigned* __restrict__ zq, int n)
{
    __shared__ float sWe[32 * 32];
    __shared__ float sWt[32 * 8];
    __shared__ float sBe[32];
    __shared__ float sBt[8];
    for (int i = threadIdx.x; i < 32 * 32; i += 256) sWe[i] = we[i];
    for (int i = threadIdx.x; i < 32 * 8; i += 256) sWt[i] = wt[i];
    if (threadIdx.x < 32) sBe[threadIdx.x] = be[threadIdx.x];
    if (threadIdx.x < 8)  sBt[threadIdx.x] = bt[threadIdx.x];
    __syncthreads();

    int node = blockIdx.x * 256 + threadIdx.x;
    if (node >= n) return;

    float row[32];
    {
        const float4* rp = (const float4*)(in + (size_t)node * 32);
        #pragma unroll
        for (int q = 0; q < 8; q++) {
            float4 v = rp[q];
            row[4*q] = v.x; row[4*q+1] = v.y; row[4*q+2] = v.z; row[4*q+3] = v.w;
        }
    }

    float o[40];
    #pragma unroll
    for (int j = 0; j < 32; j++) o[j] = sBe[j];
    #pragma unroll
    for (int i = 0; i < 32; i++) {
        float v = row[i];
        #pragma unroll
        for (int j = 0; j < 32; j++) o[j] = fmaf(v, sWe[i * 32 + j], o[j]);
    }
    #pragma unroll
    for (int j = 0; j < 8; j++) o[32 + j] = sBt[j];
    #pragma unroll
    for (int i = 0; i < 32; i++) {
        float v = row[i];
        #pragma unroll
        for (int j = 0; j < 8; j++) o[32 + j] = fmaf(v, sWt[i * 8 + j], o[32 + j]);
    }

    unsigned b[40];
    #pragma unroll
    for (int i = 0; i < 40; i++) b[i] = enc12(relu_(o[i]));
    unsigned wd[16];
    #pragma unroll
    for (int k = 0; k < 5; k++) {
        wd[3*k+0] = b[8*k+0] | (b[8*k+1] << 12) | (b[8*k+2] << 24);
        wd[3*k+1] = (b[8*k+2] >> 8) | (b[8*k+3] << 4) | (b[8*k+4] << 16) | (b[8*k+5] << 28);
        wd[3*k+2] = (b[8*k+5] >> 4) | (b[8*k+6] << 8) | (b[8*k+7] << 20);
    }
    wd[15] = 0;
    uint4* zv = (uint4*)(zq + (size_t)node * 16);
    #pragma unroll
    for (int q = 0; q < 4; q++)
        zv[q] = make_uint4(wd[4*q], wd[4*q+1], wd[4*q+2], wd[4*q+3]);
}

// ---------------- decode+accumulate one edge ----------------
__device__ __forceinline__ void acc_edge(float* acc, float w,
    const uint4& A, const uint4& B, const uint4& C, const uint4& D)
{
    unsigned wds[15] = {A.x, A.y, A.z, A.w, B.x, B.y, B.z, B.w,
                        C.x, C.y, C.z, C.w, D.x, D.y, D.z};
    #pragma unroll
    for (int k = 0; k < 5; k++) {
        unsigned xw = wds[3*k+0], yw = wds[3*k+1], zw = wds[3*k+2];
        acc[8*k+0] = fmaf(w, dec12(xw & 0xFFFu),                       acc[8*k+0]);
        acc[8*k+1] = fmaf(w, dec12((xw >> 12) & 0xFFFu),               acc[8*k+1]);
        acc[8*k+2] = fmaf(w, dec12(((xw >> 24) | (yw << 8)) & 0xFFFu), acc[8*k+2]);
        acc[8*k+3] = fmaf(w, dec12((yw >> 4) & 0xFFFu),                acc[8*k+3]);
        acc[8*k+4] = fmaf(w, dec12((yw >> 16) & 0xFFFu),               acc[8*k+4]);
        acc[8*k+5] = fmaf(w, dec12(((yw >> 28) | (zw << 4)) & 0xFFFu), acc[8*k+5]);
        acc[8*k+6] = fmaf(w, dec12((zw >> 8) & 0xFFFu),                acc[8*k+6]);
        acc[8*k+7] = fmaf(w, dec12((zw >> 20) & 0xFFFu),               acc[8*k+7]);
    }
}

// ---------------- fused aggregate + finalize (+ optional fused z2 emit) ----------------
template <int RW, int TIN, int TOFF, bool EMITZ>
__global__ __launch_bounds__(256) void fin_kernel(
    const float* __restrict__ in,
    const unsigned* __restrict__ zq,
    const int* __restrict__ offsets,
    const unsigned* __restrict__ csr,        // 4-B records [src:19 @13][w13 @0]
    const float* __restrict__ wre, const float* __restrict__ bre,
    const float* __restrict__ wrt, const float* __restrict__ brt,
    const float* __restrict__ w2e, const float* __restrict__ b2e,
    const float* __restrict__ w2t, const float* __restrict__ b2t,
    float* __restrict__ outbuf, int nOut,
    unsigned* __restrict__ zq2,
    int n)
{
    __shared__ float sWe[64 * 32];
    __shared__ float sWt[(TIN + 8) * 8];
    __shared__ float sBe[32];
    __shared__ float sBt[8];
    __shared__ float sW2e[32 * 32];
    __shared__ float sW2t[8 * 8];
    __shared__ float sB2e[32];
    __shared__ float sB2t[8];
    for (int i = threadIdx.x; i < 64 * 32; i += 256) sWe[i] = wre[i];
    for (int i = threadIdx.x; i < (TIN + 8) * 8; i += 256) sWt[i] = wrt[i];
    if (threadIdx.x < 32) sBe[threadIdx.x] = bre[threadIdx.x];
    if (threadIdx.x < 8)  sBt[threadIdx.x] = brt[threadIdx.x];
    if (EMITZ) {
        for (int i = threadIdx.x; i < 32 * 32; i += 256) sW2e[i] = w2e[i];
        for (int i = threadIdx.x; i < 8 * 8; i += 256) sW2t[i] = w2t[i];
        if (threadIdx.x < 32) sB2e[threadIdx.x] = b2e[threadIdx.x];
        if (threadIdx.x < 8)  sB2t[threadIdx.x] = b2t[threadIdx.x];
    }
    __syncthreads();

    int node = blockIdx.x * 256 + threadIdx.x;
    if (node >= n) return;

    float acc[40];
    #pragma unroll
    for (int j = 0; j < 40; j++) acc[j] = 0.0f;
    float wsum = 1.0f;

    const float DW = 1.0f / 8191.0f;
    int e0 = offsets[node];
    int e1 = offsets[node + 1];
    int e = e0;
    for (; e + 2 <= e1; e += 2) {
        unsigned pk0 = csr[e];
        unsigned pk1 = csr[e + 1];
        const uint4* p0 = (const uint4*)(zq + (size_t)(pk0 >> 13) * 16);
        const uint4* p1 = (const uint4*)(zq + (size_t)(pk1 >> 13) * 16);
        uint4 A0 = p0[0], B0 = p0[1], C0 = p0[2], D0 = p0[3];
        uint4 A1 = p1[0], B1 = p1[1], C1 = p1[2], D1 = p1[3];
        float w0 = (float)(pk0 & 8191u) * DW;
        float w1 = (float)(pk1 & 8191u) * DW;
        acc_edge(acc, w0, A0, B0, C0, D0);
        acc_edge(acc, w1, A1, B1, C1, D1);
        wsum += w0;
        wsum += w1;
    }
    if (e < e1) {
        unsigned pk = csr[e];
        const uint4* zp = (const uint4*)(zq + (size_t)(pk >> 13) * 16);
        uint4 A = zp[0], B = zp[1], C = zp[2], D = zp[3];
        float w = (float)(pk & 8191u) * DW;
        acc_edge(acc, w, A, B, C, D);
        wsum += w;
    }
    float inv = 1.0f / wsum;
    #pragma unroll
    for (int j = 0; j < 40; j++) acc[j] *= inv;

    float row[RW];
    {
        const float4* rp = (const float4*)(in + (size_t)node * RW);
        #pragma unroll
        for (int q = 0; q < RW / 4; q++) {
            float4 v = rp[q];
            row[4*q] = v.x; row[4*q+1] = v.y; row[4*q+2] = v.z; row[4*q+3] = v.w;
        }
    }

    float h[40];

    {
        float o[32];
        #pragma unroll
        for (int j = 0; j < 32; j++) o[j] = sBe[j];
        #pragma unroll
        for (int i = 0; i < 32; i++) {
            float v = row[i];
            #pragma unroll
            for (int j = 0; j < 32; j++) o[j] = fmaf(v, sWe[i * 32 + j], o[j]);
        }
        #pragma unroll
        for (int i = 0; i < 32; i++) {
            float v = acc[i];
            #pragma unroll
            for (int j = 0; j < 32; j++) o[j] = fmaf(v, sWe[(32 + i) * 32 + j], o[j]);
        }
        #pragma unroll
        for (int j = 0; j < 32; j++) h[j] = relu_(o[j]);
    }
    {
        float ot[8];
        #pragma unroll
        for (int j = 0; j < 8; j++) ot[j] = sBt[j];
        #pragma unroll
        for (int i = 0; i < TIN; i++) {
            float v = row[TOFF + i];
            #pragma unroll
            for (int j = 0; j < 8; j++) ot[j] = fmaf(v, sWt[i * 8 + j], ot[j]);
        }
        #pragma unroll
        for (int i = 0; i < 8; i++) {
            float v = acc[32 + i];
            #pragma unroll
            for (int j = 0; j < 8; j++) ot[j] = fmaf(v, sWt[(TIN + i) * 8 + j], ot[j]);
        }
        #pragma unroll
        for (int j = 0; j < 8; j++) h[32 + j] = relu_(ot[j]);
    }

    if (node < nOut) {
        float4* ov = (float4*)(outbuf + (size_t)node * 40);
        #pragma unroll
        for (int q = 0; q < 10; q++)
            ov[q] = make_float4(h[4*q], h[4*q+1], h[4*q+2], h[4*q+3]);
    }

    if (EMITZ) {
        float z2[40];
        #pragma unroll
        for (int j = 0; j < 32; j++) z2[j] = sB2e[j];
        #pragma unroll
        for (int i = 0; i < 32; i++) {
            float v = h[i];
            #pragma unroll
            for (int j = 0; j < 32; j++) z2[j] = fmaf(v, sW2e[i * 32 + j], z2[j]);
        }
        #pragma unroll
        for (int j = 0; j < 8; j++) z2[32 + j] = sB2t[j];
        #pragma unroll
        for (int i = 0; i < 8; i++) {
            float v = h[32 + i];
            #pragma unroll
            for (int j = 0; j < 8; j++) z2[32 + j] = fmaf(v, sW2t[i * 8 + j], z2[32 + j]);
        }
        unsigned b[40];
        #pragma unroll
        for (int i = 0; i < 40; i++) b[i] = enc12(relu_(z2[i]));
        unsigned wd[16];
        #pragma unroll
        for (int k = 0; k < 5; k++) {
            wd[3*k+0] = b[8*k+0] | (b[8*k+1] << 12) | (b[8*k+2] << 24);
            wd[3*k+1] = (b[8*k+2] >> 8) | (b[8*k+3] << 4) | (b[8*k+4] << 16) | (b[8*k+5] << 28);
            wd[3*k+2] = (b[8*k+5] >> 4) | (b[8*k+6] << 8) | (b[8*k+7] << 20);
        }
        wd[15] = 0;
        uint4* zv = (uint4*)(zq2 + (size_t)node * 16);
        #pragma unroll
        for (int q = 0; q < 4; q++)
            zv[q] = make_uint4(wd[4*q], wd[4*q+1], wd[4*q+2], wd[4*q+3]);
    }
}

// ---------------- loss ----------------

__device__ __forceinline__ void load40(const float* p, float* r) {
    const float4* v = (const float4*)p;
    #pragma unroll
    for (int q = 0; q < 10; q++) {
        float4 t = v[q];
        r[4*q] = t.x; r[4*q+1] = t.y; r[4*q+2] = t.z; r[4*q+3] = t.w;
    }
}

__device__ __forceinline__ float dot40(const float* a, const float* b) {
    float s = 0.0f;
    #pragma unroll
    for (int d = 0; d < 40; d++) s = fmaf(a[d], b[d], s);
    return s;
}

__device__ __forceinline__ void softmax5(const float l[5], float q[5]) {
    float m = l[0];
    #pragma unroll
    for (int c = 1; c < 5; c++) m = fmaxf(m, l[c]);
    float s = 0.0f;
    #pragma unroll
    for (int c = 0; c < 5; c++) { q[c] = expf(l[c] - m); s += q[c]; }
    float inv = 1.0f / s;
    #pragma unroll
    for (int c = 0; c < 5; c++) q[c] *= inv;
}

__device__ __forceinline__ float ent5(const float q[5]) {
    float e = 0.0f;
    #pragma unroll
    for (int c = 0; c < 5; c++) e += q[c] * logf(q[c] + 1e-20f);
    return e;
}

__device__ __forceinline__ float dot5(const float* a, const float* b) {
    float s = 0.0f;
    #pragma unroll
    for (int c = 0; c < 5; c++) s += a[c] * b[c];
    return s;
}

__global__ __launch_bounds__(256) void loss_kernel(
    const float* __restrict__ emb,
    const float* __restrict__ cent,
    const float* __restrict__ cent_t,
    float* __restrict__ out)
{
    __shared__ float sC[5 * 40];
    for (int i = threadIdx.x; i < 200; i += 256) {
        int c = i / 40, d = i % 40;
        sC[i] = (d < 32) ? cent[c * 32 + d] : cent_t[c * 8 + (d - 32)];
    }
    __syncthreads();

    int i = blockIdx.x * 256 + threadIdx.x;
    float contrib = 0.0f;
    if (i < BQ) {
        const float* base = emb + (size_t)i * 200;

        float ctr[40];
        load40(base, ctr);
        float l[5];
        #pragma unroll
        for (int c = 0; c < 5; c++) l[c] = dot40(ctr, sC + c * 40);
        float qc[5];
        softmax5(l, qc);
        float ent = ent5(qc);

        float rowv[40];
        load40(base + 40, rowv);
        float pd = dot40(ctr, rowv);
        #pragma unroll
        for (int c = 0; c < 5; c++) l[c] = dot40(rowv, sC + c * 40);
        float qp[5];
        softmax5(l, qp);
        float cpd = dot5(qc, qp);
        ent += ent5(qp);

        float nd = -1e30f, cnd = -1e30f;
        #pragma unroll
        for (int k = 0; k < 3; k++) {
            load40(base + (2 + k) * 40, rowv);
            nd = fmaxf(nd, dot40(ctr, rowv));
            #pragma unroll
            for (int c = 0; c < 5; c++) l[c] = dot40(rowv, sC + c * 40);
            float qn[5];
            softmax5(l, qn);
            cnd = fmaxf(cnd, dot5(qc, qn));
            ent += ent5(qn);
        }

        float mm  = fmaxf(nd - pd + 1.0f, 0.0f);
        float cmm = fmaxf(cnd - cpd + 1.0f, 0.0f);
        contrib = (mm + cmm) * (1.0f / (float)BQ) + 0.01f * (1.0f / (float)BS) * ent;
    }

    #pragma unroll
    for (int off = 32; off > 0; off >>= 1) contrib += __shfl_down(contrib, off);
    if ((threadIdx.x & 63) == 0) atomicAdd(out, contrib);
}

// ---------------- launch ----------------

extern "C" void kernel_launch(void* const* d_in, const int* in_sizes, int n_in,
                              void* d_out, int out_size, void* d_ws, size_t ws_size,
                              hipStream_t stream) {
    const float* x      = (const float*)d_in[0];
    const float* weight = (const float*)d_in[1];
    const float* e_w1l  = (const float*)d_in[2];
    const float* e_b1l  = (const float*)d_in[3];
    const float* e_w1r  = (const float*)d_in[4];
    const float* e_b1r  = (const float*)d_in[5];
    const float* e_w2l  = (const float*)d_in[6];
    const float* e_b2l  = (const float*)d_in[7];
    const float* e_w2r  = (const float*)d_in[8];
    const float* e_b2r  = (const float*)d_in[9];
    const float* t_w1l  = (const float*)d_in[10];
    const float* t_b1l  = (const float*)d_in[11];
    const float* t_w1r  = (const float*)d_in[12];
    const float* t_b1r  = (const float*)d_in[13];
    const float* t_w2l  = (const float*)d_in[14];
    const float* t_b2l  = (const float*)d_in[15];
    const float* t_w2r  = (const float*)d_in[16];
    const float* t_b2r  = (const float*)d_in[17];
    const float* cent   = (const float*)d_in[18];
    const float* cent_t = (const float*)d_in[19];
    const int*   eidx   = (const int*)d_in[20];

    const int E = in_sizes[20] / 2;
    const int N = in_sizes[0] / 32;
    const int* srcI = eidx;
    const int* dstI = eidx + E;
    float* out = (float*)d_out;

    const int NC = (N + CB - 1) / CB;                    // 245 coarse buckets
    const int per = (((E + NWG - 1) / NWG) + 3) & ~3;    // WG slice, multiple of 4

    char* p = (char*)d_ws;
    auto alloc = [&](size_t bytes) -> char* {
        char* r = p;
        p += (bytes + 255) & ~(size_t)255;
        return r;
    };
    char* regionA = alloc((size_t)E * 8);                // tmp (64 MB) / zq1 (32 MB)
    ull*  tmp     = (ull*)regionA;
    unsigned* zq1 = (unsigned*)regionA;
    unsigned* zq2 = (unsigned*)alloc((size_t)N * 64);    // 32 MB
    float* hcat   = (float*)alloc((size_t)BS * 40 * 4);  // 16 MB
    float* emb    = (float*)alloc((size_t)BS * 40 * 4);  // 16 MB
    unsigned* csr = (unsigned*)alloc((size_t)E * 4);     // 32 MB
    int*   offsets= (int*)alloc((size_t)(N + 1) * 4);
    int*   hist2D = (int*)alloc((size_t)NC * NWG * 4);
    int*   wgbase = (int*)alloc((size_t)NC * NWG * 4);
    int*   bucketTot  = (int*)alloc((size_t)NC * 4);
    int*   bucketBase = (int*)alloc((size_t)NC * 4);
    (void)ws_size;

    hipMemsetAsync(d_out, 0, sizeof(float), stream);

    // binning
    hist_kernel<<<NWG, 1024, 0, stream>>>(dstI, E, NC, per, hist2D);
    reduce_kernel<<<NC, 256, 0, stream>>>(hist2D, bucketTot);
    scanTot_kernel<<<1, 256, 0, stream>>>(bucketTot, NC, bucketBase);
    scanB_kernel<<<NC, NWG, 0, stream>>>(hist2D, bucketBase, wgbase);
    fillA_kernel<<<NWG, 1024, 0, stream>>>(srcI, dstI, weight, E, NC, per, wgbase, tmp);
    fillA2B_kernel<<<NC, 1024, 0, stream>>>(tmp, wgbase, NC, N, E, csr, offsets);

    const int nb = (N + 255) / 256;
    z1_kernel<<<nb, 256, 0, stream>>>(x, e_w1l, e_b1l, t_w1l, t_b1l, zq1, N);
    fin_kernel<32, 32, 0, true><<<nb, 256, 0, stream>>>(
        x, zq1, offsets, csr,
        e_w1r, e_b1r, t_w1r, t_b1r,
        e_w2l, e_b2l, t_w2l, t_b2l,
        hcat, BS, zq2, N);
    const int nb2 = (BS + 255) / 256;
    fin_kernel<40, 8, 32, false><<<nb2, 256, 0, stream>>>(
        hcat, zq2, offsets, csr,
        e_w2r, e_b2r, t_w2r, t_b2r,
        nullptr, nullptr, nullptr, nullptr,
        emb, BS, nullptr, BS);

    loss_kernel<<<(BQ + 255) / 256, 256, 0, stream>>>(emb, cent, cent_t, out);
}